// Round 17
// baseline (191.381 us; speedup 1.0000x reference)
//
#include <hip/hip_runtime.h>
#include <hip/hip_bf16.h>

#define NTOT 8192
#define FIN 128
#define FOUT 32
#define NH 4
#define NSEG 4
#define SEGJ (NTOT / NSEG)  // 2048

typedef __attribute__((ext_vector_type(4))) float f32x4;
typedef __attribute__((ext_vector_type(4))) int i32x4;
typedef __attribute__((ext_vector_type(4))) unsigned int u32x4;
typedef __attribute__((ext_vector_type(8))) __bf16 bf16x8;
typedef unsigned long long u64;
typedef unsigned int u32;

__device__ __forceinline__ unsigned short f2bf(float x) {
  __hip_bfloat16 h = __float2bfloat16(x);
  return *reinterpret_cast<unsigned short*>(&h);
}

// ---------------- k1: h = X @ W -> h [N][128] f32, plus B-fragment panels:
// panel[(p*256 + jt)*512 + l*8 + e] (bf16), p = hd*2+half,
//   value = h[node = jt*32 + (l>>4)*8 + e][p*16 + (l&15)]
__global__ __launch_bounds__(256, 2) void k1_project(
    const float* __restrict__ X, const float* __restrict__ W,
    float* __restrict__ h, unsigned short* __restrict__ panel) {
  __shared__ float Xs[32 * 128];
  __shared__ float Ws[32 * 128];
  __shared__ unsigned short Hs[128 * 40];  // [o][node_local], stride 40
  int t = threadIdx.x;
  int nb = blockIdx.x * 32;

  const f32x4* Xg = reinterpret_cast<const f32x4*>(X + (size_t)nb * FIN);
  f32x4* Xs4 = reinterpret_cast<f32x4*>(Xs);
#pragma unroll
  for (int r = 0; r < 4; ++r) Xs4[t + r * 256] = Xg[t + r * 256];

  int ng = t >> 5, oq = t & 31;
  int n0 = ng * 4, o0 = oq * 4;
  f32x4 acc[4];
#pragma unroll
  for (int nn = 0; nn < 4; ++nn) acc[nn] = (f32x4){0.f, 0.f, 0.f, 0.f};

  for (int kp = 0; kp < 4; ++kp) {
    __syncthreads();
#pragma unroll
    for (int r = 0; r < 4; ++r) {
      int q = t + r * 256;
      int flat = q * 4;
      int kk = flat >> 7;
      int c = flat & 127;
      int hdd = c >> 5;
      int oo = c & 31;
      *reinterpret_cast<f32x4*>(&Ws[kk * 128 + c]) =
          *reinterpret_cast<const f32x4*>(W + hdd * (FIN * FOUT) +
                                          (kp * 32 + kk) * FOUT + oo);
    }
    __syncthreads();
#pragma unroll 8
    for (int kk = 0; kk < 32; ++kk) {
      f32x4 wv = *reinterpret_cast<const f32x4*>(&Ws[kk * 128 + o0]);
#pragma unroll
      for (int nn = 0; nn < 4; ++nn)
        acc[nn] += Xs[(n0 + nn) * 128 + kp * 32 + kk] * wv;
    }
  }
#pragma unroll
  for (int nn = 0; nn < 4; ++nn) {
    *reinterpret_cast<f32x4*>(&h[(size_t)(nb + n0 + nn) * 128 + o0]) = acc[nn];
#pragma unroll
    for (int c = 0; c < 4; ++c)
      Hs[(o0 + c) * 40 + (n0 + nn)] = f2bf(acc[nn][c]);
  }
  __syncthreads();
  int jt = blockIdx.x;
#pragma unroll
  for (int it = 0; it < 2; ++it) {
    int item = t + it * 256;
    int p = item >> 6;
    int l = item & 63;
    int o = p * 16 + (l & 15);
    u32x4 v = *reinterpret_cast<const u32x4*>(&Hs[o * 40 + (l >> 4) * 8]);
    *reinterpret_cast<u32x4*>(panel + (size_t)(p * 256 + jt) * 512 + l * 8) = v;
  }
}

// ---------------- k2: two-plane tables.
// Sf/E1f/E2f f32 [hd][N]; Dbf/F1bf/F2bf bf16 [jm][hd][64] (jm = j>>6)
__global__ __launch_bounds__(256, 2) void k2_scores(
    const float* __restrict__ h, const float* __restrict__ a_src,
    const float* __restrict__ a_dst, float* __restrict__ Sf,
    float* __restrict__ E1f, float* __restrict__ E2f,
    unsigned short* __restrict__ Dbf, unsigned short* __restrict__ F1bf,
    unsigned short* __restrict__ F2bf) {
  int n = blockIdx.x * 256 + threadIdx.x;
  const f32x4* hv = reinterpret_cast<const f32x4*>(h + (size_t)n * 128);
  const f32x4* as4 = reinterpret_cast<const f32x4*>(a_src);
  const f32x4* ad4 = reinterpret_cast<const f32x4*>(a_dst);
  int jm = n >> 6, jo = n & 63;
#pragma unroll
  for (int hd = 0; hd < NH; ++hd) {
    f32x4 sa = {0.f, 0.f, 0.f, 0.f}, da = {0.f, 0.f, 0.f, 0.f};
#pragma unroll
    for (int q = 0; q < 8; ++q) {
      f32x4 x = hv[hd * 8 + q];
      sa += x * as4[hd * 8 + q];
      da += x * ad4[hd * 8 + q];
    }
    float s = (sa[0] + sa[1]) + (sa[2] + sa[3]);
    float d = (da[0] + da[1]) + (da[2] + da[3]);
    Sf[hd * NTOT + n] = s;
    E1f[hd * NTOT + n] = expf(s);
    E2f[hd * NTOT + n] = expf(0.2f * s);
    int ti = (jm * 4 + hd) * 64 + jo;
    Dbf[ti] = f2bf(d);
    F1bf[ti] = f2bf(expf(d));
    F2bf[ti] = f2bf(expf(0.2f * d));
  }
}

// ---------------- k3: fused adj-read + two-plane masked-table softmax + PV.
// L1-BW-optimized: tables staged ONCE to 48 KB LDS (broadcast reads on the
// LDS pipe, not vL1D), M=32 rows/wave (2 row-groups amortize every panel
// read). Wave = 32 rows x 2 heads; block = 4 waves = 64 rows x all 4 heads.
// L1 traffic: 24 KB -> 16 KB per macro-wave at twice the rows.
__global__ __launch_bounds__(256)
__attribute__((amdgpu_waves_per_eu(2))) void k3_attn(
    const int* __restrict__ adj, const float* __restrict__ Sf,
    const float* __restrict__ E1f, const float* __restrict__ E2f,
    const unsigned short* __restrict__ Dbf,
    const unsigned short* __restrict__ F1bf,
    const unsigned short* __restrict__ F2bf,
    const unsigned short* __restrict__ panel, float* __restrict__ pacc,
    float* __restrict__ plsum) {
  const int N = NTOT;
  __shared__ char lds[49152];  // D @0, F1 @16384, F2 @32768 (16 KB each)
  int tid = threadIdx.x;
  int w = tid >> 6, l = tid & 63;
  int rh = w & 1, hp = w >> 1;
  int itile = blockIdx.x >> 2, seg = blockIdx.x & 3;
  int rowblock = itile * 64 + rh * 32;
  int m = l & 15, g = l >> 4, jc = g * 8;
  int hd0 = hp * 2;

  // ---- one-time table staging: 48 KB, coalesced, single barrier ----
  {
    const char* gD = (const char*)Dbf + (size_t)seg * 16384;
    const char* gF1 = (const char*)F1bf + (size_t)seg * 16384;
    const char* gF2 = (const char*)F2bf + (size_t)seg * 16384;
#pragma unroll
    for (int it = 0; it < 4; ++it) {
      int off = it * 4096 + tid * 16;
      *(u32x4*)&lds[off] = *(const u32x4*)(gD + off);
      *(u32x4*)&lds[16384 + off] = *(const u32x4*)(gF1 + off);
      *(u32x4*)&lds[32768 + off] = *(const u32x4*)(gF2 + off);
    }
  }
  __syncthreads();

  float sv[2][2];  // [hh][rg]
#pragma unroll
  for (int hh = 0; hh < 2; ++hh)
#pragma unroll
    for (int rg = 0; rg < 2; ++rg)
      sv[hh][rg] = Sf[(hd0 + hh) * N + rowblock + rg * 16 + m];

  const int* adjr0 = adj + (size_t)(rowblock + m) * N + seg * SEGJ + jc;
  const int* adjr1 = adjr0 + (size_t)16 * N;
  const char* panB = (const char*)panel + (size_t)l * 16;

  f32x4 z4 = {0.f, 0.f, 0.f, 0.f};
  f32x4 aP0[4] = {z4, z4, z4, z4}, aP1[4] = {z4, z4, z4, z4},
        aPs[4] = {z4, z4, z4, z4};
  f32x4 aN0[4] = {z4, z4, z4, z4}, aN1[4] = {z4, z4, z4, z4},
        aNs[4] = {z4, z4, z4, z4};
  bf16x8 bones;
  {
    u32 pat = (m == 0) ? 0x3f803f80u : 0u;
    u32x4 tmp = {pat, pat, pat, pat};
    bones = *reinterpret_cast<bf16x8*>(&tmp);
  }

#define MFM(AF, B, ACC) \
  ACC = __builtin_amdgcn_mfma_f32_16x16x32_bf16(AF, B, ACC, 0, 0, 0);

  // masked two-plane frags + 6 MFMA for one (head hh, row-group rg, jtile)
#define AFPLANE(IX, MK, Dv, F1v, F2v, B0, B1, SV)                         \
  {                                                                       \
    u32x4 aPw, aNw;                                                       \
    _Pragma("unroll") for (int p = 0; p < 4; ++p) {                       \
      float de = __uint_as_float((Dv)[p] << 16);                          \
      float dodd = __uint_as_float((Dv)[p] & 0xFFFF0000u);                \
      u32 n0 = (u32)(__float_as_int((SV) + de) >> 31);                    \
      u32 n1 = (u32)(__float_as_int((SV) + dodd) >> 31);                  \
      u32 mn = __builtin_amdgcn_perm(n1, n0, 0x05040100u);                \
      aPw[p] = (F1v)[p] & ((MK)[p] & ~mn);                                \
      aNw[p] = (F2v)[p] & ((MK)[p] & mn);                                 \
    }                                                                     \
    bf16x8 afP = *reinterpret_cast<bf16x8*>(&aPw);                        \
    bf16x8 afN = *reinterpret_cast<bf16x8*>(&aNw);                        \
    MFM(afP, B0, aP0[IX]) MFM(afP, B1, aP1[IX]) MFM(afP, bones, aPs[IX])  \
    MFM(afN, B0, aN0[IX]) MFM(afN, B1, aN1[IX]) MFM(afN, bones, aNs[IX])  \
  }

#pragma unroll 1
  for (int t = 0; t < 32; ++t) {
    // ---- adj loads: 2 row-groups x 2 jtiles x 2 = 8 i32x4 (L1) ----
    const int* a0_ = adjr0 + t * 64;
    const int* a1_ = adjr1 + t * 64;
    i32x4 r0A0 = *(const i32x4*)(a0_), r0A1 = *(const i32x4*)(a0_ + 4);
    i32x4 r0B0 = *(const i32x4*)(a0_ + 32), r0B1 = *(const i32x4*)(a0_ + 36);
    i32x4 r1A0 = *(const i32x4*)(a1_), r1A1 = *(const i32x4*)(a1_ + 4);
    i32x4 r1B0 = *(const i32x4*)(a1_ + 32), r1B1 = *(const i32x4*)(a1_ + 36);
    // ---- adjacency halfword masks: mk[rg][jt] ----
    u32x4 mk[2][2];
#define MKB(DST, A0, A1)                                                    \
  DST[0] = __builtin_amdgcn_perm((u32)(-(A0)[1]), (u32)(-(A0)[0]),          \
                                 0x05040100u);                              \
  DST[1] = __builtin_amdgcn_perm((u32)(-(A0)[3]), (u32)(-(A0)[2]),          \
                                 0x05040100u);                              \
  DST[2] = __builtin_amdgcn_perm((u32)(-(A1)[1]), (u32)(-(A1)[0]),          \
                                 0x05040100u);                              \
  DST[3] = __builtin_amdgcn_perm((u32)(-(A1)[3]), (u32)(-(A1)[2]),          \
                                 0x05040100u);
    MKB(mk[0][0], r0A0, r0A1)
    MKB(mk[0][1], r0B0, r0B1)
    MKB(mk[1][0], r1A0, r1A1)
    MKB(mk[1][1], r1B0, r1B1)
#undef MKB

#pragma unroll
    for (int hh = 0; hh < 2; ++hh) {
      int hd = hd0 + hh;
      // tables from LDS: broadcast reads, conflict-free (groups hit
      // disjoint bank quads)
      int tb = t * 512 + hd * 128 + g * 16;
      u32x4 DvA = *(const u32x4*)&lds[tb];
      u32x4 DvB = *(const u32x4*)&lds[tb + 64];
      u32x4 F1A = *(const u32x4*)&lds[16384 + tb];
      u32x4 F1B = *(const u32x4*)&lds[16384 + tb + 64];
      u32x4 F2A = *(const u32x4*)&lds[32768 + tb];
      u32x4 F2B = *(const u32x4*)&lds[32768 + tb + 64];
      // panels from L1: plane p = hd*2 (o 0-15), hd*2+1 (o 16-31)
      size_t jtg = (size_t)(seg * 64 + t * 2);
      const char* p0 = panB + ((size_t)(hd * 2) * 256 + jtg) * 1024;
      const char* p1 = panB + ((size_t)(hd * 2 + 1) * 256 + jtg) * 1024;
      bf16x8 B0A = *(const bf16x8*)(p0);
      bf16x8 B0B = *(const bf16x8*)(p0 + 1024);
      bf16x8 B1A = *(const bf16x8*)(p1);
      bf16x8 B1B = *(const bf16x8*)(p1 + 1024);
#pragma unroll
      for (int rg = 0; rg < 2; ++rg) {
        float sv_ = sv[hh][rg];
        AFPLANE(hh * 2 + rg, mk[rg][0], DvA, F1A, F2A, B0A, B1A, sv_)
        AFPLANE(hh * 2 + rg, mk[rg][1], DvB, F1B, F2B, B0B, B1B, sv_)
      }
    }
  }
#undef AFPLANE
#undef MFM

  // epilogue: D layout col=lane&15 (o), row=(lane>>4)*4+reg (i).
#pragma unroll
  for (int hh = 0; hh < 2; ++hh) {
#pragma unroll
    for (int rg = 0; rg < 2; ++rg) {
      int hd = hd0 + hh;
      int ix = hh * 2 + rg;
      int rb = rowblock + rg * 16 + g * 4;
#pragma unroll
      for (int r = 0; r < 4; ++r) {
        int rowr = rb + r;
        float e1 = E1f[hd * N + rowr], e2 = E2f[hd * N + rowr];
        if (m == 0)
          plsum[(seg * NH + hd) * N + rowr] =
              e1 * aPs[ix][r] + e2 * aNs[ix][r];
        pacc[((size_t)seg * N + rowr) * 128 + hd * 32 + m] =
            e1 * aP0[ix][r] + e2 * aN0[ix][r];
        pacc[((size_t)seg * N + rowr) * 128 + hd * 32 + 16 + m] =
            e1 * aP1[ix][r] + e2 * aN1[ix][r];
      }
    }
  }
}

// ---------------- k4: combine segments + normalize
__global__ __launch_bounds__(256, 2) void k4_combine(
    const float* __restrict__ pacc, const float* __restrict__ plsum,
    float* __restrict__ out) {
  int idx = blockIdx.x * 256 + threadIdx.x;
  int i = idx >> 7;
  int c = idx & 127;
  int hd = c >> 5;
  float a = 0.f, ls = 0.f;
#pragma unroll
  for (int s = 0; s < NSEG; ++s) {
    a += pacc[((size_t)s * NTOT + i) * 128 + c];
    ls += plsum[(s * NH + hd) * NTOT + i];
  }
  out[idx] = (ls > 0.f) ? a / ls : 0.f;
}

extern "C" void kernel_launch(void* const* d_in, const int* in_sizes, int n_in,
                              void* d_out, int out_size, void* d_ws,
                              size_t ws_size, hipStream_t stream) {
  const float* X = (const float*)d_in[0];
  const int* adj = (const int*)d_in[1];
  const float* W = (const float*)d_in[2];
  const float* a_src = (const float*)d_in[3];
  const float* a_dst = (const float*)d_in[4];
  float* out = (float*)d_out;

  char* ws = (char*)d_ws;
  float* h = (float*)(ws + 0x0);                              // 4 MB
  unsigned short* panel = (unsigned short*)(ws + 0x400000);   // 2 MB
  float* Sf = (float*)(ws + 0x600000);                        // 128 KB
  float* E1f = (float*)(ws + 0x620000);                       // 128 KB
  float* E2f = (float*)(ws + 0x640000);                       // 128 KB
  unsigned short* Dbf = (unsigned short*)(ws + 0x660000);     // 64 KB
  unsigned short* F1bf = (unsigned short*)(ws + 0x670000);    // 64 KB
  unsigned short* F2bf = (unsigned short*)(ws + 0x680000);    // 64 KB
  float* pacc = (float*)(ws + 0x700000);                      // 16 MB
  float* plsum = (float*)(ws + 0x1700000);                    // 512 KB

  k1_project<<<dim3(256), dim3(256), 0, stream>>>(X, W, h, panel);
  k2_scores<<<dim3(32), dim3(256), 0, stream>>>(h, a_src, a_dst, Sf, E1f, E2f,
                                                Dbf, F1bf, F2bf);
  k3_attn<<<dim3(128 * NSEG), dim3(256), 0, stream>>>(
      adj, Sf, E1f, E2f, Dbf, F1bf, F2bf, panel, pacc, plsum);
  k4_combine<<<dim3(4096), dim3(256), 0, stream>>>(pacc, plsum, out);
}

// Round 18
// 155.742 us; speedup vs baseline: 1.2288x; 1.2288x over previous
//
#include <hip/hip_runtime.h>
#include <hip/hip_bf16.h>

#define NTOT 8192
#define FIN 128
#define FOUT 32
#define NH 4
#define NSEG 4
#define SEGJ (NTOT / NSEG)  // 2048
#define LOG2E 1.4426950408889634f

typedef __attribute__((ext_vector_type(4))) float f32x4;
typedef __attribute__((ext_vector_type(4))) int i32x4;
typedef __attribute__((ext_vector_type(4))) unsigned int u32x4;
typedef __attribute__((ext_vector_type(8))) __bf16 bf16x8;
typedef unsigned long long u64;
typedef unsigned int u32;

__device__ __forceinline__ unsigned short f2bf(float x) {
  __hip_bfloat16 h = __float2bfloat16(x);
  return *reinterpret_cast<unsigned short*>(&h);
}

__device__ __forceinline__ float fexp2(float y) {
  float p;
  asm("v_exp_f32 %0, %1" : "=v"(p) : "v"(y));
  return p;
}

// async global->LDS DMA: LDS dst = (wave-uniform base) + lane*16 (HW-added);
// global src is per-lane (we pre-swizzle it).
__device__ __forceinline__ void dma16(const void* g, void* l) {
  __builtin_amdgcn_global_load_lds(
      (const __attribute__((address_space(1))) void*)g,
      (__attribute__((address_space(3))) void*)l, 16, 0, 0);
}

// ---------------- k1: h = X @ W -> h [N][128] f32, plus B-fragment panels:
// panel[(p*256 + jt)*512 + l*8 + e] (bf16), p = hd*2+half,
//   value = h[node = jt*32 + (l>>4)*8 + e][p*16 + (l&15)]
__global__ __launch_bounds__(256, 2) void k1_project(
    const float* __restrict__ X, const float* __restrict__ W,
    float* __restrict__ h, unsigned short* __restrict__ panel) {
  __shared__ float Xs[32 * 128];
  __shared__ float Ws[32 * 128];
  __shared__ unsigned short Hs[128 * 40];  // [o][node_local], stride 40
  int t = threadIdx.x;
  int nb = blockIdx.x * 32;

  const f32x4* Xg = reinterpret_cast<const f32x4*>(X + (size_t)nb * FIN);
  f32x4* Xs4 = reinterpret_cast<f32x4*>(Xs);
#pragma unroll
  for (int r = 0; r < 4; ++r) Xs4[t + r * 256] = Xg[t + r * 256];

  int ng = t >> 5, oq = t & 31;
  int n0 = ng * 4, o0 = oq * 4;
  f32x4 acc[4];
#pragma unroll
  for (int nn = 0; nn < 4; ++nn) acc[nn] = (f32x4){0.f, 0.f, 0.f, 0.f};

  for (int kp = 0; kp < 4; ++kp) {
    __syncthreads();
#pragma unroll
    for (int r = 0; r < 4; ++r) {
      int q = t + r * 256;
      int flat = q * 4;
      int kk = flat >> 7;
      int c = flat & 127;
      int hdd = c >> 5;
      int oo = c & 31;
      *reinterpret_cast<f32x4*>(&Ws[kk * 128 + c]) =
          *reinterpret_cast<const f32x4*>(W + hdd * (FIN * FOUT) +
                                          (kp * 32 + kk) * FOUT + oo);
    }
    __syncthreads();
#pragma unroll 8
    for (int kk = 0; kk < 32; ++kk) {
      f32x4 wv = *reinterpret_cast<const f32x4*>(&Ws[kk * 128 + o0]);
#pragma unroll
      for (int nn = 0; nn < 4; ++nn)
        acc[nn] += Xs[(n0 + nn) * 128 + kp * 32 + kk] * wv;
    }
  }
#pragma unroll
  for (int nn = 0; nn < 4; ++nn) {
    *reinterpret_cast<f32x4*>(&h[(size_t)(nb + n0 + nn) * 128 + o0]) = acc[nn];
#pragma unroll
    for (int c = 0; c < 4; ++c)
      Hs[(o0 + c) * 40 + (n0 + nn)] = f2bf(acc[nn][c]);
  }
  __syncthreads();
  int jt = blockIdx.x;
#pragma unroll
  for (int it = 0; it < 2; ++it) {
    int item = t + it * 256;
    int p = item >> 6;
    int l = item & 63;
    int o = p * 16 + (l & 15);
    u32x4 v = *reinterpret_cast<const u32x4*>(&Hs[o * 40 + (l >> 4) * 8]);
    *reinterpret_cast<u32x4*>(panel + (size_t)(p * 256 + jt) * 512 + l * 8) = v;
  }
}

// ---------------- k2: per-node scores (x log2e). Sl2 [hd][N]; Dt [jm][hd][64]
__global__ __launch_bounds__(256, 2) void k2_scores(
    const float* __restrict__ h, const float* __restrict__ a_src,
    const float* __restrict__ a_dst, float* __restrict__ Sl2,
    float* __restrict__ Dt) {
  int n = blockIdx.x * 256 + threadIdx.x;
  const f32x4* hv = reinterpret_cast<const f32x4*>(h + (size_t)n * 128);
  const f32x4* as4 = reinterpret_cast<const f32x4*>(a_src);
  const f32x4* ad4 = reinterpret_cast<const f32x4*>(a_dst);
#pragma unroll
  for (int hd = 0; hd < NH; ++hd) {
    f32x4 sa = {0.f, 0.f, 0.f, 0.f}, da = {0.f, 0.f, 0.f, 0.f};
#pragma unroll
    for (int q = 0; q < 8; ++q) {
      f32x4 x = hv[hd * 8 + q];
      sa += x * as4[hd * 8 + q];
      da += x * ad4[hd * 8 + q];
    }
    float s = (sa[0] + sa[1]) + (sa[2] + sa[3]);
    float d = (da[0] + da[1]) + (da[2] + da[3]);
    Sl2[hd * NTOT + n] = s * LOG2E;
    Dt[(n >> 6) * 256 + hd * 64 + (n & 63)] = d * LOG2E;
  }
}

// ---------------- k3: fused adj-read + masked softmax + PV.
// R11 structure (wave = 16 rows x 4 heads, 4 waves/block = 64 rows) with ONE
// change: adj is staged into per-wave-private LDS via global_load_lds with
// PERFECTLY SEQUENTIAL per-row 1KB DMAs (16 lines each, stream-friendly),
// replacing the 16-line-scattered direct loads (measured ~127 cyc/inst vs
// ~15 for coalesced). XOR swizzle rides on the GLOBAL source address (m173),
// LDS reads are spread conflict-free. Per-wave regions -> zero barriers.
__global__ __launch_bounds__(256)
__attribute__((amdgpu_waves_per_eu(2))) void k3_attn(
    const int* __restrict__ adj, const float* __restrict__ Sl2,
    const float* __restrict__ Dt, const unsigned short* __restrict__ panel,
    float* __restrict__ pacc, float* __restrict__ plsum) {
  const int N = NTOT;
  __shared__ char adjS[4 * 16384];  // 64 KB: per-wave 16 rows x 1KB (4 macros)
  int tid = threadIdx.x;
  int w = tid >> 6, l = tid & 63;
  int itile = blockIdx.x >> 2, seg = blockIdx.x & 3;
  int ibase = itile * 64;
  int m = l & 15, g = l >> 4, jc = g * 8;
  int row = ibase + w * 16 + m;
  int seg0 = seg * 32;  // first 64-j macro of this segment (32 per seg)

  float svv[4];
#pragma unroll
  for (int hd = 0; hd < 4; ++hd) svv[hd] = Sl2[hd * N + row];

  char* myS = adjS + w * 16384;
  // wave's adj byte base: rows [ibase+w*16, +16), this segment's j-range
  const char* adjB =
      (const char*)adj + ((size_t)(ibase + w * 16) * N + seg * SEGJ) * 4;
  int lsw = l * 16;  // lane's linear 16B slot within a row's 1KB chunk

  f32x4 z4 = {0.f, 0.f, 0.f, 0.f};
  f32x4 c0[4] = {z4, z4, z4, z4}, c1[4] = {z4, z4, z4, z4},
        cs[4] = {z4, z4, z4, z4};
  bf16x8 bones;
  {
    u32 pat = (m == 0) ? 0x3f803f80u : 0u;
    u32x4 tmp = {pat, pat, pat, pat};
    bones = *reinterpret_cast<bf16x8*>(&tmp);
  }

  // stage super-step sup_: 16 DMAs, row i's contiguous 1KB (pre-swizzled src)
#define STAGE(sup_)                                                      \
  {                                                                      \
    _Pragma("unroll") for (int i = 0; i < 16; ++i) {                     \
      const char* g_ = adjB + (size_t)i * (N * 4) + (sup_)*1024 +        \
                       (size_t)(lsw ^ ((i & 7) << 4));                   \
      dma16(g_, myS + i * 1024);                                         \
    }                                                                    \
  }

  // masked A-frag: y = LeakyReLU(s+d)*log2e, gated to -1e9 by adj, exp2
#define AFSEL(AF, AV0, AV1, DA, DB, SV)                                  \
  {                                                                      \
    f32x4 xa_ = (DA) + (SV);                                             \
    f32x4 xb_ = (DB) + (SV);                                             \
    f32x4 ya_ = __builtin_elementwise_max(xa_, 0.2f * xa_);              \
    f32x4 yb_ = __builtin_elementwise_max(xb_, 0.2f * xb_);              \
    _Pragma("unroll") for (int e = 0; e < 4; ++e) {                      \
      float y_ = ((AV0)[e] != 0) ? ya_[e] : -1e9f;                       \
      AF[e] = (__bf16)fexp2(y_);                                         \
    }                                                                    \
    _Pragma("unroll") for (int e = 0; e < 4; ++e) {                      \
      float y_ = ((AV1)[e] != 0) ? yb_[e] : -1e9f;                       \
      AF[e + 4] = (__bf16)fexp2(y_);                                     \
    }                                                                    \
  }

#define MFM(AF, B, ACC) \
  ACC = __builtin_amdgcn_mfma_f32_16x16x32_bf16(AF, B, ACC, 0, 0, 0);

  // full macro: 4 heads x (2 k-halves x 3 MFMA); adj from LDS
#define MATHM(t_, A0, A1, A2, A3)                                         \
  {                                                                       \
    int jm_ = seg0 + (t_);                                                \
    const float* db_ = Dt + (size_t)jm_ * 256;                            \
    const unsigned short* pb_ =                                           \
        panel + (size_t)(seg * 64 + (t_)*2) * 512 + l * 8;                \
    _Pragma("unroll") for (int hd = 0; hd < 4; ++hd) {                    \
      f32x4 d0 = *(const f32x4*)(db_ + hd * 64 + jc);                     \
      f32x4 d1 = *(const f32x4*)(db_ + hd * 64 + jc + 4);                 \
      f32x4 d2 = *(const f32x4*)(db_ + hd * 64 + 32 + jc);                \
      f32x4 d3 = *(const f32x4*)(db_ + hd * 64 + 32 + jc + 4);            \
      const unsigned short* p0_ = pb_ + (size_t)(hd * 2) * 131072;        \
      const unsigned short* p1_ = pb_ + (size_t)(hd * 2 + 1) * 131072;    \
      bf16x8 B0a = *(const bf16x8*)(p0_);                                 \
      bf16x8 B1a = *(const bf16x8*)(p1_);                                 \
      bf16x8 B0b = *(const bf16x8*)(p0_ + 512);                           \
      bf16x8 B1b = *(const bf16x8*)(p1_ + 512);                           \
      float sv_ = svv[hd];                                                \
      bf16x8 af_;                                                         \
      AFSEL(af_, A0, A1, d0, d1, sv_)                                     \
      MFM(af_, B0a, c0[hd]) MFM(af_, B1a, c1[hd]) MFM(af_, bones, cs[hd]) \
      AFSEL(af_, A2, A3, d2, d3, sv_)                                     \
      MFM(af_, B0b, c0[hd]) MFM(af_, B1b, c1[hd]) MFM(af_, bones, cs[hd]) \
    }                                                                     \
  }

  STAGE(0)
  int swz = (m & 7) << 4;
  const char* rb_ = myS + m * 1024;

#pragma unroll 1
  for (int sup = 0; sup < 8; ++sup) {
    // stage 'sup' landed (per-wave DMAs); memory clobber orders the reads
    asm volatile("s_waitcnt vmcnt(0)" ::: "memory");
    __builtin_amdgcn_sched_barrier(0);
#pragma unroll
    for (int mm = 0; mm < 4; ++mm) {
      int base_ = mm * 256 + g * 32;
      i32x4 a0 = *(const i32x4*)(rb_ + ((base_ + 0) ^ swz));
      i32x4 a1 = *(const i32x4*)(rb_ + ((base_ + 16) ^ swz));
      i32x4 a2 = *(const i32x4*)(rb_ + ((base_ + 128) ^ swz));
      i32x4 a3 = *(const i32x4*)(rb_ + ((base_ + 144) ^ swz));
      MATHM(sup * 4 + mm, a0, a1, a2, a3)
    }
    // all ds_reads of this super-step retired before the slot is re-staged
    asm volatile("s_waitcnt lgkmcnt(0)" ::: "memory");
    __builtin_amdgcn_sched_barrier(0);
    if (sup < 7) STAGE(sup + 1)
  }
#undef STAGE
#undef AFSEL
#undef MFM
#undef MATHM

  // epilogue: D layout col=lane&15 (o), row=(lane>>4)*4+reg (i)
#pragma unroll
  for (int hd = 0; hd < 4; ++hd) {
    int rb = ibase + w * 16 + g * 4;
    if (m == 0) {
#pragma unroll
      for (int r = 0; r < 4; ++r)
        plsum[(seg * NH + hd) * N + rb + r] = cs[hd][r];
    }
#pragma unroll
    for (int r = 0; r < 4; ++r) {
      int rowr = rb + r;
      pacc[((size_t)seg * N + rowr) * 128 + hd * 32 + m] = c0[hd][r];
      pacc[((size_t)seg * N + rowr) * 128 + hd * 32 + 16 + m] = c1[hd][r];
    }
  }
}

// ---------------- k4: combine segments + normalize
__global__ __launch_bounds__(256, 2) void k4_combine(
    const float* __restrict__ pacc, const float* __restrict__ plsum,
    float* __restrict__ out) {
  int idx = blockIdx.x * 256 + threadIdx.x;
  int i = idx >> 7;
  int c = idx & 127;
  int hd = c >> 5;
  float a = 0.f, ls = 0.f;
#pragma unroll
  for (int s = 0; s < NSEG; ++s) {
    a += pacc[((size_t)s * NTOT + i) * 128 + c];
    ls += plsum[(s * NH + hd) * NTOT + i];
  }
  out[idx] = (ls > 0.f) ? a / ls : 0.f;
}

extern "C" void kernel_launch(void* const* d_in, const int* in_sizes, int n_in,
                              void* d_out, int out_size, void* d_ws,
                              size_t ws_size, hipStream_t stream) {
  const float* X = (const float*)d_in[0];
  const int* adj = (const int*)d_in[1];
  const float* W = (const float*)d_in[2];
  const float* a_src = (const float*)d_in[3];
  const float* a_dst = (const float*)d_in[4];
  float* out = (float*)d_out;

  char* ws = (char*)d_ws;
  float* h = (float*)(ws + 0x0);                             // 4 MB
  unsigned short* panel = (unsigned short*)(ws + 0x400000);  // 2 MB
  float* Sl2 = (float*)(ws + 0x600000);                      // 128 KB
  float* Dt = (float*)(ws + 0x620000);                       // 128 KB
  float* pacc = (float*)(ws + 0x700000);                     // 16 MB
  float* plsum = (float*)(ws + 0x1700000);                   // 512 KB

  k1_project<<<dim3(256), dim3(256), 0, stream>>>(X, W, h, panel);
  k2_scores<<<dim3(32), dim3(256), 0, stream>>>(h, a_src, a_dst, Sl2, Dt);
  k3_attn<<<dim3(128 * NSEG), dim3(256), 0, stream>>>(adj, Sl2, Dt, panel,
                                                      pacc, plsum);
  k4_combine<<<dim3(4096), dim3(256), 0, stream>>>(pacc, plsum, out);
}